// Round 14
// baseline (283.261 us; speedup 1.0000x reference)
//
#include <hip/hip_runtime.h>
#include <hip/hip_bf16.h>

typedef __attribute__((ext_vector_type(4))) float  f32x4;
typedef __attribute__((ext_vector_type(4))) float  float4v;
typedef __attribute__((ext_vector_type(8))) short  bf16x8;
typedef __attribute__((ext_vector_type(4))) short  bf16x4;
typedef __attribute__((ext_vector_type(2))) unsigned int u32x2;

#define BZ   32
#define SLEN 1024
#define TLEN 1024
#define DIM  512
#define TILE 128
#define LP   40   // LDS row pitch (shorts) for score/proj (R5 best config)

#define PSEL 0x07060302u

__device__ __forceinline__ unsigned int fbits(float x) { return __builtin_bit_cast(unsigned int, x); }
__device__ __forceinline__ float fval(unsigned int u) { return __builtin_bit_cast(float, u); }

__device__ __forceinline__ unsigned short f2bf(float x) {   // RNE
  unsigned int u = fbits(x);
  unsigned int r = u + 0x7FFFu + ((u >> 16) & 1u);
  return (unsigned short)(r >> 16);
}
__device__ __forceinline__ float bf2f(unsigned short h) { return fval(((unsigned int)h) << 16); }

__device__ __forceinline__ unsigned int packhi(float x0, float x1) {
  return __builtin_amdgcn_perm(fbits(x1), fbits(x0), PSEL);
}

// global -> LDS direct 16B/lane. LDS dest = wave-uniform base + lane*16.
__device__ __forceinline__ void gld16(const void* g, void* l) {
  __builtin_amdgcn_global_load_lds(
      (const __attribute__((address_space(1))) void*)g,
      (__attribute__((address_space(3))) void*)l, 16, 0, 0);
}

// src_lengths may land as int64 or int32; values are in [1,1024] so in the
// int64 layout every odd 32-bit word is 0, while int32 layout has p[1]>=1.
__device__ __forceinline__ int get_len(const int* __restrict__ p, int b) {
  bool is64 = (p[1] == 0) && (p[3] == 0) && (p[5] == 0);
  return is64 ? p[2 * b] : p[b];
}

// ---------------------------------------------------------------- K0: src -> srcT (bf16)
#define TLP 68
__global__ __launch_bounds__(256) void k_transpose(
    const float* __restrict__ src, unsigned short* __restrict__ srcT) {
  const int b  = blockIdx.z;
  const int s0 = blockIdx.x * 64;
  const int d0 = blockIdx.y * 64;
  __shared__ unsigned short tl[64 * TLP];
  const int tid = threadIdx.x;
#pragma unroll
  for (int r = 0; r < 4; ++r) {
    const int idx = tid + 256 * r;
    const int row = idx >> 4, c4 = idx & 15;
    float4v x = *(const float4v*)(src + ((size_t)(b * SLEN + s0 + row)) * DIM + d0 + c4 * 4);
    unsigned short* pp = tl + row * TLP + c4 * 4;
    pp[0] = f2bf(x[0]); pp[1] = f2bf(x[1]); pp[2] = f2bf(x[2]); pp[3] = f2bf(x[3]);
  }
  __syncthreads();
#pragma unroll
  for (int r = 0; r < 2; ++r) {
    const int idx  = tid + 256 * r;
    const int drow = idx >> 3, c8 = idx & 7;
    union { unsigned short u[8]; bf16x8 v; } pk;
#pragma unroll
    for (int j = 0; j < 8; ++j) pk.u[j] = tl[(c8 * 8 + j) * TLP + drow];
    *(bf16x8*)(srcT + ((size_t)(b * DIM + d0 + drow)) * SLEN + s0 + c8 * 8) = pk.v;
  }
}

// ---------------------------------------------------------------- prep: w_out -> bf16 (RNE)
__global__ __launch_bounds__(256) void k_prep_w(
    const float* __restrict__ w, unsigned short* __restrict__ wbf) {
  const size_t i = ((size_t)blockIdx.x * 256 + threadIdx.x) * 8;
  float4v x0 = *(const float4v*)(w + i);
  float4v x1 = *(const float4v*)(w + i + 4);
  union { unsigned short u[8]; bf16x8 v; } hi;
#pragma unroll
  for (int j = 0; j < 4; ++j) { hi.u[j] = f2bf(x0[j]); hi.u[4 + j] = f2bf(x1[j]); }
  *(bf16x8*)(wbf + i) = hi.v;
}

// ---------------------------------------------------------------- K1: score = tgt @ src^T (3xbf16, trunc-split) [R5 body]
__global__ __launch_bounds__(256) void k_score(
    const float* __restrict__ tgt, const float* __restrict__ src,
    const int* __restrict__ lens, float* __restrict__ align_out) {
  const int j    = blockIdx.x;
  const int xcd  = j & 7;
  const int seq  = j >> 3;
  const int b    = ((seq >> 6) << 3) | xcd;   // batch->XCD pinned
  const int tile = seq & 63;
  const int t0   = (tile >> 3) * TILE;
  const int s0   = (tile & 7) * TILE;
  const int len  = get_len(lens, b);
  if (s0 >= len) return;   // fully-masked tile: softmax writes the zeros

  __shared__ short aHi[TILE * LP], aLo[TILE * LP], bHi[TILE * LP], bLo[TILE * LP];

  const int tid  = threadIdx.x;
  const int lane = tid & 63;
  const int wid  = tid >> 6;
  const int wt   = wid >> 1, wsd = wid & 1;
  const int g    = lane >> 4, r16 = lane & 15;
  const int srow = tid >> 3, sc4 = tid & 7;

  f32x4 acc[4][4];
#pragma unroll
  for (int m = 0; m < 4; ++m)
#pragma unroll
    for (int n = 0; n < 4; ++n) acc[m][n] = (f32x4){0.f, 0.f, 0.f, 0.f};

  const float* tgtB = tgt + ((size_t)(b * TLEN + t0)) * DIM;
  const float* srcB = src + ((size_t)(b * SLEN + s0)) * DIM;

  float4v va[4], vb[4];
#pragma unroll
  for (int r = 0; r < 4; ++r) {
    const int row = srow + 32 * r;
    va[r] = *(const float4v*)(tgtB + (size_t)row * DIM + sc4 * 4);
    vb[r] = *(const float4v*)(srcB + (size_t)row * DIM + sc4 * 4);
  }

  for (int k0 = 0; k0 < DIM; k0 += 32) {
#pragma unroll
    for (int r = 0; r < 4; ++r) {
      const int row = srow + 32 * r;
      u32x2 ah, al, bh, bl;
      ah[0] = packhi(va[r][0], va[r][1]); ah[1] = packhi(va[r][2], va[r][3]);
      bh[0] = packhi(vb[r][0], vb[r][1]); bh[1] = packhi(vb[r][2], vb[r][3]);
      float ra0 = va[r][0] - fval(fbits(va[r][0]) & 0xFFFF0000u);
      float ra1 = va[r][1] - fval(fbits(va[r][1]) & 0xFFFF0000u);
      float ra2 = va[r][2] - fval(fbits(va[r][2]) & 0xFFFF0000u);
      float ra3 = va[r][3] - fval(fbits(va[r][3]) & 0xFFFF0000u);
      float rb0 = vb[r][0] - fval(fbits(vb[r][0]) & 0xFFFF0000u);
      float rb1 = vb[r][1] - fval(fbits(vb[r][1]) & 0xFFFF0000u);
      float rb2 = vb[r][2] - fval(fbits(vb[r][2]) & 0xFFFF0000u);
      float rb3 = vb[r][3] - fval(fbits(vb[r][3]) & 0xFFFF0000u);
      al[0] = packhi(ra0, ra1); al[1] = packhi(ra2, ra3);
      bl[0] = packhi(rb0, rb1); bl[1] = packhi(rb2, rb3);
      const int o = row * LP + sc4 * 4;
      *(u32x2*)(aHi + o) = ah; *(u32x2*)(aLo + o) = al;
      *(u32x2*)(bHi + o) = bh; *(u32x2*)(bLo + o) = bl;
    }
    if (k0 + 32 < DIM) {
#pragma unroll
      for (int r = 0; r < 4; ++r) {
        const int row = srow + 32 * r;
        va[r] = *(const float4v*)(tgtB + (size_t)row * DIM + (k0 + 32) + sc4 * 4);
        vb[r] = *(const float4v*)(srcB + (size_t)row * DIM + (k0 + 32) + sc4 * 4);
      }
    }
    __syncthreads();
    bf16x8 fbh[4], fbl[4];
#pragma unroll
    for (int n = 0; n < 4; ++n) {
      const int row = wsd * 64 + n * 16 + r16;
      fbh[n] = *(const bf16x8*)(bHi + row * LP + g * 8);
      fbl[n] = *(const bf16x8*)(bLo + row * LP + g * 8);
    }
#pragma unroll
    for (int m = 0; m < 4; ++m) {
      const int row = wt * 64 + m * 16 + r16;
      bf16x8 fah = *(const bf16x8*)(aHi + row * LP + g * 8);
      bf16x8 fal = *(const bf16x8*)(aLo + row * LP + g * 8);
#pragma unroll
      for (int n = 0; n < 4; ++n) {
        acc[m][n] = __builtin_amdgcn_mfma_f32_16x16x32_bf16(fah, fbh[n], acc[m][n], 0, 0, 0);
        acc[m][n] = __builtin_amdgcn_mfma_f32_16x16x32_bf16(fal, fbh[n], acc[m][n], 0, 0, 0);
        acc[m][n] = __builtin_amdgcn_mfma_f32_16x16x32_bf16(fah, fbl[n], acc[m][n], 0, 0, 0);
      }
    }
    __syncthreads();
  }
  float* outB = align_out + ((size_t)(b * TLEN + t0)) * SLEN + s0;
#pragma unroll
  for (int m = 0; m < 4; ++m) {
    const int tr = wt * 64 + m * 16 + g * 4;
#pragma unroll
    for (int n = 0; n < 4; ++n) {
      const int sc = wsd * 64 + n * 16 + r16;
#pragma unroll
      for (int r = 0; r < 4; ++r)
        outB[(size_t)(tr + r) * SLEN + sc] = acc[m][n][r];
    }
  }
}

// ---------------------------------------------------------------- K2: masked softmax (in-place) + bf16 p copy
__global__ __launch_bounds__(256) void k_softmax(
    const int* __restrict__ lens, float* __restrict__ align_io,
    unsigned short* __restrict__ pbf) {
  const int row  = blockIdx.x * 4 + (threadIdx.x >> 6);  // b*1024 + t
  const int lane = threadIdx.x & 63;
  const int b    = row >> 10;
  const int len  = get_len(lens, b);
  float* p = align_io + (size_t)row * SLEN;
  float v[4][4];
  float mx = -3.0e38f;
#pragma unroll
  for (int q = 0; q < 4; ++q) {
    if (256 * q >= len) {
#pragma unroll
      for (int j = 0; j < 4; ++j) v[q][j] = 0.f;
      continue;
    }
    const int sb = (lane + 64 * q) * 4;
    float4v x = *(const float4v*)(p + sb);
#pragma unroll
    for (int j = 0; j < 4; ++j) {
      v[q][j] = (sb + j < len) ? x[j] : 0.f;
      if (sb + j < len) mx = fmaxf(mx, x[j]);
    }
  }
#pragma unroll
  for (int off = 1; off < 64; off <<= 1) mx = fmaxf(mx, __shfl_xor(mx, off));
  float sum = 0.f;
#pragma unroll
  for (int q = 0; q < 4; ++q) {
    const int sb = (lane + 64 * q) * 4;
#pragma unroll
    for (int j = 0; j < 4; ++j) {
      float e = (sb + j < len) ? __expf(v[q][j] - mx) : 0.f;
      v[q][j] = e; sum += e;
    }
  }
#pragma unroll
  for (int off = 1; off < 64; off <<= 1) sum += __shfl_xor(sum, off);
  const float inv = 1.f / sum;
  unsigned short* pb = pbf + (size_t)row * SLEN;
#pragma unroll
  for (int q = 0; q < 4; ++q) {
    float4v x;
#pragma unroll
    for (int j = 0; j < 4; ++j) x[j] = v[q][j] * inv;
    *(float4v*)(p + (lane + 64 * q) * 4) = x;
    u32x2 h;                                     // trunc-bf16 copy for PV A-operand
    h[0] = packhi(x[0], x[1]); h[1] = packhi(x[2], x[3]);
    *(u32x2*)(pb + (lane + 64 * q) * 4) = h;
  }
}

// ---------------------------------------------------------------- K3: c = p @ src  (pure-bf16, global_load_lds staging)
// A from pbf, B from srcT; 16KB linear LDS [128][32]; m97 2-barrier loop.
__global__ __launch_bounds__(256) void k_pv(
    const unsigned short* __restrict__ pbf, const unsigned short* __restrict__ srcT,
    const int* __restrict__ lens, unsigned short* __restrict__ cws) {
  const int j    = blockIdx.x;
  const int xcd  = j & 7;
  const int seq  = j >> 3;
  const int b    = ((seq >> 5) << 3) | xcd;
  const int tile = seq & 31;
  const int t0   = (tile >> 2) * TILE;
  const int d0   = (tile & 3) * TILE;
  const int len  = get_len(lens, b);
  const int ksteps = (len + 31) >> 5;    // pbf is zero-padded past len -> pad-safe

  __shared__ short A[TILE * 32], B[TILE * 32];

  const int tid  = threadIdx.x;
  const int lane = tid & 63;
  const int w    = tid >> 6;
  const int wt   = w >> 1, wsd = w & 1;
  const int g    = lane >> 4, r16 = lane & 15;

  // staging: wave w stages rows [w*32, w*32+32); lane -> row += lane>>2, col8 = (lane&3)*8
  const unsigned short* gA = pbf  + ((size_t)(b * TLEN + t0 + w * 32 + (lane >> 2))) * SLEN + (lane & 3) * 8;
  const unsigned short* gB = srcT + ((size_t)(b * DIM  + d0 + w * 32 + (lane >> 2))) * SLEN + (lane & 3) * 8;
  const size_t rstep = (size_t)16 * SLEN;   // +16 rows
  short* lA = A + (w * 32) * 32;
  short* lB = B + (w * 32) * 32;

  f32x4 acc[4][4];
#pragma unroll
  for (int m = 0; m < 4; ++m)
#pragma unroll
    for (int n = 0; n < 4; ++n) acc[m][n] = (f32x4){0.f, 0.f, 0.f, 0.f};

  for (int ks = 0; ks < ksteps; ++ks) {
    const int k0 = ks * 32;
    gld16(gA + k0,         lA);
    gld16(gA + k0 + rstep, lA + 16 * 32);
    gld16(gB + k0,         lB);
    gld16(gB + k0 + rstep, lB + 16 * 32);
    __syncthreads();   // drains vmcnt -> tiles visible

    bf16x8 fb[4];
#pragma unroll
    for (int n = 0; n < 4; ++n)
      fb[n] = *(const bf16x8*)(B + (wsd * 64 + n * 16 + r16) * 32 + g * 8);
#pragma unroll
    for (int m = 0; m < 4; ++m) {
      bf16x8 fa = *(const bf16x8*)(A + (wt * 64 + m * 16 + r16) * 32 + g * 8);
#pragma unroll
      for (int n = 0; n < 4; ++n)
        acc[m][n] = __builtin_amdgcn_mfma_f32_16x16x32_bf16(fa, fb[n], acc[m][n], 0, 0, 0);
    }
    __syncthreads();
  }
#pragma unroll
  for (int m = 0; m < 4; ++m) {
    const int tr = wt * 64 + m * 16 + g * 4;
#pragma unroll
    for (int n = 0; n < 4; ++n) {
      const int dc = wsd * 64 + n * 16 + r16;
#pragma unroll
      for (int r = 0; r < 4; ++r)
        cws[((size_t)(b * TLEN + t0 + tr + r)) * DIM + d0 + dc] = f2bf(acc[m][n][r]);
    }
  }
}

// ---------------------------------------------------------------- K4: attn_h = [c,tgt] @ w_out^T (bf16) [R11 body]
__global__ __launch_bounds__(256) void k_proj(
    const unsigned short* __restrict__ cws, const float* __restrict__ tgt,
    const unsigned short* __restrict__ wbf, float* __restrict__ attn_out) {
  const int j    = blockIdx.x;
  const int xcd  = j & 7;
  const int seq  = j >> 3;
  const int b    = ((seq >> 5) << 3) | xcd;
  const int tile = seq & 31;
  const int t0   = (tile >> 2) * TILE;
  const int d0   = (tile & 3) * TILE;

  __shared__ short A[TILE * LP], B[TILE * LP];
  const int tid  = threadIdx.x;
  const int lane = tid & 63;
  const int wid  = tid >> 6;
  const int wt   = wid >> 1, wsd = wid & 1;
  const int g    = lane >> 4, r16 = lane & 15;

  f32x4 acc[4][4];
#pragma unroll
  for (int m = 0; m < 4; ++m)
#pragma unroll
    for (int n = 0; n < 4; ++n) acc[m][n] = (f32x4){0.f, 0.f, 0.f, 0.f};

  for (int k0 = 0; k0 < 2 * DIM; k0 += 32) {
    if (k0 < DIM) {
#pragma unroll
      for (int r = 0; r < 2; ++r) {
        const int row = (tid >> 2) + 64 * r, c8 = tid & 3;
        bf16x8 x = *(const bf16x8*)(cws + ((size_t)(b * TLEN + t0 + row)) * DIM + k0 + c8 * 8);
        *(bf16x8*)(A + row * LP + c8 * 8) = x;
      }
    } else {
#pragma unroll
      for (int r = 0; r < 4; ++r) {
        const int row = (tid >> 3) + 32 * r, c4 = tid & 7;
        float4v x = *(const float4v*)(tgt + ((size_t)(b * TLEN + t0 + row)) * DIM + (k0 - DIM) + c4 * 4);
        bf16x4 h;
#pragma unroll
        for (int j2 = 0; j2 < 4; ++j2) h[j2] = (short)f2bf(x[j2]);
        *(bf16x4*)(A + row * LP + c4 * 4) = h;
      }
    }
#pragma unroll
    for (int r = 0; r < 2; ++r) {
      const int row = (tid >> 2) + 64 * r, c8 = tid & 3;
      bf16x8 x = *(const bf16x8*)(wbf + ((size_t)(d0 + row)) * (2 * DIM) + k0 + c8 * 8);
      *(bf16x8*)(B + row * LP + c8 * 8) = x;
    }
    __syncthreads();
    bf16x8 fb[4];
#pragma unroll
    for (int n = 0; n < 4; ++n) fb[n] = *(const bf16x8*)(B + (wsd * 64 + n * 16 + r16) * LP + g * 8);
#pragma unroll
    for (int m = 0; m < 4; ++m) {
      bf16x8 fa = *(const bf16x8*)(A + (wt * 64 + m * 16 + r16) * LP + g * 8);
#pragma unroll
      for (int n = 0; n < 4; ++n)
        acc[m][n] = __builtin_amdgcn_mfma_f32_16x16x32_bf16(fa, fb[n], acc[m][n], 0, 0, 0);
    }
    __syncthreads();
  }
#pragma unroll
  for (int m = 0; m < 4; ++m) {
    const int tr = wt * 64 + m * 16 + g * 4;
#pragma unroll
    for (int n = 0; n < 4; ++n) {
      const int dc = wsd * 64 + n * 16 + r16;
#pragma unroll
      for (int r = 0; r < 4; ++r)
        attn_out[((size_t)(b * TLEN + t0 + tr + r)) * DIM + d0 + dc] = acc[m][n][r];
    }
  }
}

extern "C" void kernel_launch(void* const* d_in, const int* in_sizes, int n_in,
                              void* d_out, int out_size, void* d_ws, size_t ws_size,
                              hipStream_t stream) {
  const float* src   = (const float*)d_in[0];
  const float* tgt   = (const float*)d_in[1];
  const int*   lens  = (const int*)d_in[2];
  const float* w_out = (const float*)d_in[3];

  float* attn_out  = (float*)d_out;                          // 32*1024*512 f32
  float* align_out = attn_out + (size_t)BZ * TLEN * DIM;     // 32*1024*1024 f32

  const size_t NE = (size_t)BZ * SLEN * DIM;
  const size_t NW = (size_t)DIM * 2 * DIM;
  const size_t NP = (size_t)BZ * TLEN * SLEN;
  unsigned short* srcT = (unsigned short*)d_ws;
  unsigned short* cws  = srcT + NE;
  unsigned short* wbf  = cws + NE;
  unsigned short* pbf  = wbf + NW;

  k_transpose<<<dim3(16, 8, BZ), 256, 0, stream>>>(src, srcT);
  k_prep_w<<<dim3((unsigned)(NW / 8 / 256)), 256, 0, stream>>>(w_out, wbf);
  k_score<<<dim3(2048), 256, 0, stream>>>(tgt, src, lens, align_out);
  k_softmax<<<dim3(BZ * TLEN / 4), 256, 0, stream>>>(lens, align_out, pbf);
  k_pv<<<dim3(1024), 256, 0, stream>>>(pbf, srcT, lens, cws);
  k_proj<<<dim3(1024), 256, 0, stream>>>(cws, tgt, wbf, attn_out);
}

// Round 15
// 261.711 us; speedup vs baseline: 1.0823x; 1.0823x over previous
//
#include <hip/hip_runtime.h>
#include <hip/hip_bf16.h>

typedef __attribute__((ext_vector_type(4))) float  f32x4;
typedef __attribute__((ext_vector_type(4))) float  float4v;
typedef __attribute__((ext_vector_type(8))) short  bf16x8;
typedef __attribute__((ext_vector_type(4))) short  bf16x4;
typedef __attribute__((ext_vector_type(2))) unsigned int u32x2;

#define BZ   32
#define SLEN 1024
#define TLEN 1024
#define DIM  512
#define TILE 128
#define LP   40   // LDS row pitch (shorts): 80B rows (best measured config)

// v_perm selector: out = [hi16(src0_arg) : hi16(src1_arg)]
#define PSEL 0x07060302u

__device__ __forceinline__ unsigned int fbits(float x) { return __builtin_bit_cast(unsigned int, x); }
__device__ __forceinline__ float fval(unsigned int u) { return __builtin_bit_cast(float, u); }

__device__ __forceinline__ unsigned short f2bf(float x) {   // RNE (off hot path)
  unsigned int u = fbits(x);
  unsigned int r = u + 0x7FFFu + ((u >> 16) & 1u);
  return (unsigned short)(r >> 16);
}
__device__ __forceinline__ float bf2f(unsigned short h) { return fval(((unsigned int)h) << 16); }

// pack trunc-bf16 of (x0,x1) -> u32 [bf(x1)<<16 | bf(x0)]
__device__ __forceinline__ unsigned int packhi(float x0, float x1) {
  return __builtin_amdgcn_perm(fbits(x1), fbits(x0), PSEL);
}

// src_lengths may land as int64 or int32; values are in [1,1024] so in the
// int64 layout every odd 32-bit word is 0, while int32 layout has p[1]>=1.
__device__ __forceinline__ int get_len(const int* __restrict__ p, int b) {
  bool is64 = (p[1] == 0) && (p[3] == 0) && (p[5] == 0);
  return is64 ? p[2 * b] : p[b];
}

// ---------------------------------------------------------------- K0: src -> srcT (bf16)
#define TLP 68
__global__ __launch_bounds__(256) void k_transpose(
    const float* __restrict__ src, unsigned short* __restrict__ srcT) {
  const int b  = blockIdx.z;
  const int s0 = blockIdx.x * 64;
  const int d0 = blockIdx.y * 64;
  __shared__ unsigned short tl[64 * TLP];
  const int tid = threadIdx.x;
#pragma unroll
  for (int r = 0; r < 4; ++r) {
    const int idx = tid + 256 * r;
    const int row = idx >> 4, c4 = idx & 15;   // row: s, c4: d/4
    float4v x = *(const float4v*)(src + ((size_t)(b * SLEN + s0 + row)) * DIM + d0 + c4 * 4);
    unsigned short* pp = tl + row * TLP + c4 * 4;
    pp[0] = f2bf(x[0]); pp[1] = f2bf(x[1]); pp[2] = f2bf(x[2]); pp[3] = f2bf(x[3]);
  }
  __syncthreads();
#pragma unroll
  for (int r = 0; r < 2; ++r) {
    const int idx  = tid + 256 * r;
    const int drow = idx >> 3, c8 = idx & 7;   // drow: d, c8: s/8
    union { unsigned short u[8]; bf16x8 v; } pk;
#pragma unroll
    for (int j = 0; j < 8; ++j) pk.u[j] = tl[(c8 * 8 + j) * TLP + drow];
    *(bf16x8*)(srcT + ((size_t)(b * DIM + d0 + drow)) * SLEN + s0 + c8 * 8) = pk.v;
  }
}

// ---------------------------------------------------------------- prep: w_out -> bf16 (RNE)
__global__ __launch_bounds__(256) void k_prep_w(
    const float* __restrict__ w, unsigned short* __restrict__ wbf) {
  const size_t i = ((size_t)blockIdx.x * 256 + threadIdx.x) * 8;
  float4v x0 = *(const float4v*)(w + i);
  float4v x1 = *(const float4v*)(w + i + 4);
  union { unsigned short u[8]; bf16x8 v; } hi;
#pragma unroll
  for (int j = 0; j < 4; ++j) { hi.u[j] = f2bf(x0[j]); hi.u[4 + j] = f2bf(x1[j]); }
  *(bf16x8*)(wbf + i) = hi.v;
}

// ---------------------------------------------------------------- K1: score = tgt @ src^T (3xbf16, trunc-split)
// Reg-prefetch pipeline + batch->XCD pinned dispatch.
__global__ __launch_bounds__(256) void k_score(
    const float* __restrict__ tgt, const float* __restrict__ src,
    const int* __restrict__ lens, float* __restrict__ align_out) {
  const int j    = blockIdx.x;
  const int xcd  = j & 7;
  const int seq  = j >> 3;
  const int b    = ((seq >> 6) << 3) | xcd;   // 4 batch-groups of 8
  const int tile = seq & 63;
  const int t0   = (tile >> 3) * TILE;
  const int s0   = (tile & 7) * TILE;
  const int len  = get_len(lens, b);
  if (s0 >= len) return;   // fully-masked tile: softmax writes the zeros

  __shared__ short aHi[TILE * LP], aLo[TILE * LP], bHi[TILE * LP], bLo[TILE * LP];

  const int tid  = threadIdx.x;
  const int lane = tid & 63;
  const int wid  = tid >> 6;
  const int wt   = wid >> 1, wsd = wid & 1;    // 2x2 waves, 64x64 each
  const int g    = lane >> 4, r16 = lane & 15;
  const int srow = tid >> 3, sc4 = tid & 7;

  f32x4 acc[4][4];
#pragma unroll
  for (int m = 0; m < 4; ++m)
#pragma unroll
    for (int n = 0; n < 4; ++n) acc[m][n] = (f32x4){0.f, 0.f, 0.f, 0.f};

  const float* tgtB = tgt + ((size_t)(b * TLEN + t0)) * DIM;
  const float* srcB = src + ((size_t)(b * SLEN + s0)) * DIM;

  float4v va[4], vb[4];
#pragma unroll
  for (int r = 0; r < 4; ++r) {   // prologue: prefetch k0 = 0
    const int row = srow + 32 * r;
    va[r] = *(const float4v*)(tgtB + (size_t)row * DIM + sc4 * 4);
    vb[r] = *(const float4v*)(srcB + (size_t)row * DIM + sc4 * 4);
  }

  for (int k0 = 0; k0 < DIM; k0 += 32) {
    // phase 1: convert current regs -> LDS (vmcnt wait on prefetch lands here)
#pragma unroll
    for (int r = 0; r < 4; ++r) {
      const int row = srow + 32 * r;
      u32x2 ah, al, bh, bl;
      ah[0] = packhi(va[r][0], va[r][1]); ah[1] = packhi(va[r][2], va[r][3]);
      bh[0] = packhi(vb[r][0], vb[r][1]); bh[1] = packhi(vb[r][2], vb[r][3]);
      float ra0 = va[r][0] - fval(fbits(va[r][0]) & 0xFFFF0000u);
      float ra1 = va[r][1] - fval(fbits(va[r][1]) & 0xFFFF0000u);
      float ra2 = va[r][2] - fval(fbits(va[r][2]) & 0xFFFF0000u);
      float ra3 = va[r][3] - fval(fbits(va[r][3]) & 0xFFFF0000u);
      float rb0 = vb[r][0] - fval(fbits(vb[r][0]) & 0xFFFF0000u);
      float rb1 = vb[r][1] - fval(fbits(vb[r][1]) & 0xFFFF0000u);
      float rb2 = vb[r][2] - fval(fbits(vb[r][2]) & 0xFFFF0000u);
      float rb3 = vb[r][3] - fval(fbits(vb[r][3]) & 0xFFFF0000u);
      al[0] = packhi(ra0, ra1); al[1] = packhi(ra2, ra3);
      bl[0] = packhi(rb0, rb1); bl[1] = packhi(rb2, rb3);
      const int o = row * LP + sc4 * 4;
      *(u32x2*)(aHi + o) = ah; *(u32x2*)(aLo + o) = al;
      *(u32x2*)(bHi + o) = bh; *(u32x2*)(bLo + o) = bl;
    }
    // phase 2: issue next K-step loads (consumed after MFMA+barrier)
    if (k0 + 32 < DIM) {
#pragma unroll
      for (int r = 0; r < 4; ++r) {
        const int row = srow + 32 * r;
        va[r] = *(const float4v*)(tgtB + (size_t)row * DIM + (k0 + 32) + sc4 * 4);
        vb[r] = *(const float4v*)(srcB + (size_t)row * DIM + (k0 + 32) + sc4 * 4);
      }
    }
    __syncthreads();
    // phase 3: frags + MFMA (B hoisted, A per-m to limit VGPR peak)
    bf16x8 fbh[4], fbl[4];
#pragma unroll
    for (int n = 0; n < 4; ++n) {
      const int row = wsd * 64 + n * 16 + r16;
      fbh[n] = *(const bf16x8*)(bHi + row * LP + g * 8);
      fbl[n] = *(const bf16x8*)(bLo + row * LP + g * 8);
    }
#pragma unroll
    for (int m = 0; m < 4; ++m) {
      const int row = wt * 64 + m * 16 + r16;
      bf16x8 fah = *(const bf16x8*)(aHi + row * LP + g * 8);
      bf16x8 fal = *(const bf16x8*)(aLo + row * LP + g * 8);
#pragma unroll
      for (int n = 0; n < 4; ++n) {
        acc[m][n] = __builtin_amdgcn_mfma_f32_16x16x32_bf16(fah, fbh[n], acc[m][n], 0, 0, 0);
        acc[m][n] = __builtin_amdgcn_mfma_f32_16x16x32_bf16(fal, fbh[n], acc[m][n], 0, 0, 0);
        acc[m][n] = __builtin_amdgcn_mfma_f32_16x16x32_bf16(fah, fbl[n], acc[m][n], 0, 0, 0);
      }
    }
    __syncthreads();
  }
  float* outB = align_out + ((size_t)(b * TLEN + t0)) * SLEN + s0;
#pragma unroll
  for (int m = 0; m < 4; ++m) {
    const int tr = wt * 64 + m * 16 + g * 4;
#pragma unroll
    for (int n = 0; n < 4; ++n) {
      const int sc = wsd * 64 + n * 16 + r16;
#pragma unroll
      for (int r = 0; r < 4; ++r)
        outB[(size_t)(tr + r) * SLEN + sc] = acc[m][n][r];
    }
  }
}

// ---------------------------------------------------------------- K2: masked softmax (in-place)
__global__ __launch_bounds__(256) void k_softmax(
    const int* __restrict__ lens, float* __restrict__ align_io) {
  const int row  = blockIdx.x * 4 + (threadIdx.x >> 6);  // b*1024 + t
  const int lane = threadIdx.x & 63;
  const int b    = row >> 10;
  const int len  = get_len(lens, b);
  float* p = align_io + (size_t)row * SLEN;
  float v[4][4];
  float mx = -3.0e38f;
#pragma unroll
  for (int q = 0; q < 4; ++q) {
    if (256 * q >= len) {
#pragma unroll
      for (int j = 0; j < 4; ++j) v[q][j] = 0.f;
      continue;
    }
    const int sb = (lane + 64 * q) * 4;
    float4v x = *(const float4v*)(p + sb);
#pragma unroll
    for (int j = 0; j < 4; ++j) {
      v[q][j] = (sb + j < len) ? x[j] : 0.f;
      if (sb + j < len) mx = fmaxf(mx, x[j]);
    }
  }
#pragma unroll
  for (int off = 1; off < 64; off <<= 1) mx = fmaxf(mx, __shfl_xor(mx, off));
  float sum = 0.f;
#pragma unroll
  for (int q = 0; q < 4; ++q) {
    const int sb = (lane + 64 * q) * 4;
#pragma unroll
    for (int j = 0; j < 4; ++j) {
      float e = (sb + j < len) ? __expf(v[q][j] - mx) : 0.f;
      v[q][j] = e; sum += e;
    }
  }
#pragma unroll
  for (int off = 1; off < 64; off <<= 1) sum += __shfl_xor(sum, off);
  const float inv = 1.f / sum;
#pragma unroll
  for (int q = 0; q < 4; ++q) {
    float4v x;
#pragma unroll
    for (int j = 0; j < 4; ++j) x[j] = v[q][j] * inv;
    *(float4v*)(p + (lane + 64 * q) * 4) = x;
  }
}

// ---------------------------------------------------------------- K3: c = align @ src (bf16, K clamped, prefetch, XCD-pinned)
__global__ __launch_bounds__(256) void k_pv(
    const float* __restrict__ align_in, const unsigned short* __restrict__ srcT,
    const int* __restrict__ lens, unsigned short* __restrict__ cws) {
  const int j    = blockIdx.x;
  const int xcd  = j & 7;
  const int seq  = j >> 3;
  const int b    = ((seq >> 5) << 3) | xcd;   // 4 batch-groups of 8
  const int tile = seq & 31;
  const int t0   = (tile >> 2) * TILE;
  const int d0   = (tile & 3) * TILE;
  const int len = get_len(lens, b);
  const int ksteps = (len + 31) >> 5;

  __shared__ short A[TILE * LP], B[TILE * LP];
  const int tid  = threadIdx.x;
  const int lane = tid & 63;
  const int wid  = tid >> 6;
  const int wt   = wid >> 1, wsd = wid & 1;
  const int g    = lane >> 4, r16 = lane & 15;

  f32x4 acc[4][4];
#pragma unroll
  for (int m = 0; m < 4; ++m)
#pragma unroll
    for (int n = 0; n < 4; ++n) acc[m][n] = (f32x4){0.f, 0.f, 0.f, 0.f};

  const int arow = tid >> 3, ac4 = tid & 7;
  const int brow = tid >> 2, bc8 = tid & 3;

  float4v xa[4];
  bf16x8  xb[2];
#pragma unroll
  for (int r = 0; r < 4; ++r)
    xa[r] = *(const float4v*)(align_in + ((size_t)(b * TLEN + t0 + arow + 32 * r)) * SLEN + ac4 * 4);
#pragma unroll
  for (int r = 0; r < 2; ++r)
    xb[r] = *(const bf16x8*)(srcT + ((size_t)(b * DIM + d0 + brow + 64 * r)) * SLEN + bc8 * 8);

  for (int ks = 0; ks < ksteps; ++ks) {
#pragma unroll
    for (int r = 0; r < 4; ++r) {   // A: align rows t (trunc-bf16 ok: align in [0,1])
      u32x2 h;
      h[0] = packhi(xa[r][0], xa[r][1]); h[1] = packhi(xa[r][2], xa[r][3]);
      *(u32x2*)(A + (arow + 32 * r) * LP + ac4 * 4) = h;
    }
#pragma unroll
    for (int r = 0; r < 2; ++r)     // B: srcT rows d
      *(bf16x8*)(B + (brow + 64 * r) * LP + bc8 * 8) = xb[r];
    if (ks + 1 < ksteps) {
      const int k0 = (ks + 1) * 32;
#pragma unroll
      for (int r = 0; r < 4; ++r)
        xa[r] = *(const float4v*)(align_in + ((size_t)(b * TLEN + t0 + arow + 32 * r)) * SLEN + k0 + ac4 * 4);
#pragma unroll
      for (int r = 0; r < 2; ++r)
        xb[r] = *(const bf16x8*)(srcT + ((size_t)(b * DIM + d0 + brow + 64 * r)) * SLEN + k0 + bc8 * 8);
    }
    __syncthreads();
    bf16x8 fb[4];
#pragma unroll
    for (int n = 0; n < 4; ++n) fb[n] = *(const bf16x8*)(B + (wsd * 64 + n * 16 + r16) * LP + g * 8);
#pragma unroll
    for (int m = 0; m < 4; ++m) {
      bf16x8 fa = *(const bf16x8*)(A + (wt * 64 + m * 16 + r16) * LP + g * 8);
#pragma unroll
      for (int n = 0; n < 4; ++n)
        acc[m][n] = __builtin_amdgcn_mfma_f32_16x16x32_bf16(fa, fb[n], acc[m][n], 0, 0, 0);
    }
    __syncthreads();
  }
#pragma unroll
  for (int m = 0; m < 4; ++m) {
    const int tr = wt * 64 + m * 16 + g * 4;
#pragma unroll
    for (int n = 0; n < 4; ++n) {
      const int dc = wsd * 64 + n * 16 + r16;
#pragma unroll
      for (int r = 0; r < 4; ++r)
        cws[((size_t)(b * TLEN + t0 + tr + r)) * DIM + d0 + dc] = f2bf(acc[m][n][r]);
    }
  }
}

// ---------------------------------------------------------------- K4: attn_h = [c,tgt] @ w_out^T (bf16, XCD-pinned)
__global__ __launch_bounds__(256) void k_proj(
    const unsigned short* __restrict__ cws, const float* __restrict__ tgt,
    const unsigned short* __restrict__ wbf, float* __restrict__ attn_out) {
  const int j    = blockIdx.x;
  const int xcd  = j & 7;
  const int seq  = j >> 3;
  const int b    = ((seq >> 5) << 3) | xcd;
  const int tile = seq & 31;
  const int t0   = (tile >> 2) * TILE;
  const int d0   = (tile & 3) * TILE;

  __shared__ short A[TILE * LP], B[TILE * LP];
  const int tid  = threadIdx.x;
  const int lane = tid & 63;
  const int wid  = tid >> 6;
  const int wt   = wid >> 1, wsd = wid & 1;
  const int g    = lane >> 4, r16 = lane & 15;

  f32x4 acc[4][4];
#pragma unroll
  for (int m = 0; m < 4; ++m)
#pragma unroll
    for (int n = 0; n < 4; ++n) acc[m][n] = (f32x4){0.f, 0.f, 0.f, 0.f};

  for (int k0 = 0; k0 < 2 * DIM; k0 += 32) {
    if (k0 < DIM) {   // A from c (already bf16)
#pragma unroll
      for (int r = 0; r < 2; ++r) {
        const int row = (tid >> 2) + 64 * r, c8 = tid & 3;
        bf16x8 x = *(const bf16x8*)(cws + ((size_t)(b * TLEN + t0 + row)) * DIM + k0 + c8 * 8);
        *(bf16x8*)(A + row * LP + c8 * 8) = x;
      }
    } else {          // A from tgt (f32 -> bf16 RNE, margin for the fp32 output)
#pragma unroll
      for (int r = 0; r < 4; ++r) {
        const int row = (tid >> 3) + 32 * r, c4 = tid & 7;
        float4v x = *(const float4v*)(tgt + ((size_t)(b * TLEN + t0 + row)) * DIM + (k0 - DIM) + c4 * 4);
        bf16x4 h;
#pragma unroll
        for (int j2 = 0; j2 < 4; ++j2) h[j2] = (short)f2bf(x[j2]);
        *(bf16x4*)(A + row * LP + c4 * 4) = h;
      }
    }
#pragma unroll
    for (int r = 0; r < 2; ++r) {   // B: wbf rows d, cols e (bf16 copy)
      const int row = (tid >> 2) + 64 * r, c8 = tid & 3;
      bf16x8 x = *(const bf16x8*)(wbf + ((size_t)(d0 + row)) * (2 * DIM) + k0 + c8 * 8);
      *(bf16x8*)(B + row * LP + c8 * 8) = x;
    }
    __syncthreads();
    bf16x8 fb[4];
#pragma unroll
    for (int n = 0; n < 4; ++n) fb[n] = *(const bf16x8*)(B + (wsd * 64 + n * 16 + r16) * LP + g * 8);
#pragma unroll
    for (int m = 0; m < 4; ++m) {
      bf16x8 fa = *(const bf16x8*)(A + (wt * 64 + m * 16 + r16) * LP + g * 8);
#pragma unroll
      for (int n = 0; n < 4; ++n)
        acc[m][n] = __builtin_amdgcn_mfma_f32_16x16x32_bf16(fa, fb[n], acc[m][n], 0, 0, 0);
    }
    __syncthreads();
  }
#pragma unroll
  for (int m = 0; m < 4; ++m) {
    const int tr = wt * 64 + m * 16 + g * 4;
#pragma unroll
    for (int n = 0; n < 4; ++n) {
      const int dc = wsd * 64 + n * 16 + r16;
#pragma unroll
      for (int r = 0; r < 4; ++r)
        attn_out[((size_t)(b * TLEN + t0 + tr + r)) * DIM + d0 + dc] = acc[m][n][r];
    }
  }
}

extern "C" void kernel_launch(void* const* d_in, const int* in_sizes, int n_in,
                              void* d_out, int out_size, void* d_ws, size_t ws_size,
                              hipStream_t stream) {
  const float* src   = (const float*)d_in[0];
  const float* tgt   = (const float*)d_in[1];
  const int*   lens  = (const int*)d_in[2];
  const float* w_out = (const float*)d_in[3];

  float* attn_out  = (float*)d_out;                          // 32*1024*512 f32
  float* align_out = attn_out + (size_t)BZ * TLEN * DIM;     // 32*1024*1024 f32

  const size_t NE = (size_t)BZ * SLEN * DIM;
  const size_t NW = (size_t)DIM * 2 * DIM;
  unsigned short* srcT = (unsigned short*)d_ws;
  unsigned short* cws  = srcT + NE;
  unsigned short* wbf  = cws + NE;

  k_transpose<<<dim3(16, 8, BZ), 256, 0, stream>>>(src, srcT);
  k_prep_w<<<dim3((unsigned)(NW / 8 / 256)), 256, 0, stream>>>(w_out, wbf);
  k_score<<<dim3(2048), 256, 0, stream>>>(tgt, src, lens, align_out);
  k_softmax<<<dim3(BZ * TLEN / 4), 256, 0, stream>>>(lens, align_out);
  k_pv<<<dim3(1024), 256, 0, stream>>>(align_out, srcT, lens, cws);
  k_proj<<<dim3(1024), 256, 0, stream>>>(cws, tgt, wbf, attn_out);
}